// Round 6
// baseline (280.990 us; speedup 1.0000x reference)
//
#include <hip/hip_runtime.h>
#include <stdint.h>

typedef __attribute__((ext_vector_type(4))) float f32x4;
typedef __attribute__((ext_vector_type(8))) short bf16x8;
typedef __attribute__((ext_vector_type(4))) unsigned int u32x4;

#define C_NORM_LOG2E 0.18033688011112043f

// 128B-row swizzle (rows of 64 bf16 / 32 f32: XOR row&7 into byte bits 4-6)
__device__ __forceinline__ uint32_t swz(uint32_t a) { return a ^ (((a >> 7) & 7u) << 4); }
// 64B-row swizzle for the P half-tile (XOR (row>>1)&3 into bits 4-5; row-preserving)
__device__ __forceinline__ uint32_t swzP(uint32_t a) { return a ^ (((a >> 7) & 3u) << 4); }

__device__ __forceinline__ uint32_t cvt_pk_bf16(float a, float b) {
  uint32_t r;
  asm("v_cvt_pk_bf16_f32 %0, %1, %2" : "=v"(r) : "v"(a), "v"(b));
  return r;
}

__device__ __forceinline__ float2 unpk_bf16(uint32_t u) {
  float2 f;
  f.x = __uint_as_float(u << 16);
  f.y = __uint_as_float(u & 0xffff0000u);
  return f;
}

__device__ __forceinline__ ushort f2bf(float f) {
  uint32_t u = __float_as_uint(f);
  u += 0x7FFFu + ((u >> 16) & 1u);
  return (ushort)(u >> 16);
}

__device__ __forceinline__ void gl_lds16(const void* gp, void* lp) {
  __builtin_amdgcn_global_load_lds((const __attribute__((address_space(1))) void*)gp,
                                   (__attribute__((address_space(3))) void*)lp, 16, 0, 0);
}

// ---- pack: Wp [192][512] bf16 (Wq|Wk|Wv), PEdT[m][n] = PE[2n][2m]*NORM*log2e,
// ----       zero cnt[128], and zero all odd output rows (16 MB) ----
__global__ void pack_kernel(const float* __restrict__ Wk, const float* __restrict__ Wq,
                            const float* __restrict__ Wv, const float* __restrict__ PE,
                            ushort* __restrict__ Wp, float* __restrict__ PEdT,
                            unsigned* __restrict__ cnt, float* __restrict__ out) {
  int bid = blockIdx.x;
  if (bid < 384) {
    int i = bid * 256 + threadIdx.x;  // 192*512
    int n = i >> 9, e = i & 511;
    float val = (n < 64) ? Wq[n * 512 + e]
              : (n < 128) ? Wk[(n - 64) * 512 + e]
                          : Wv[(n - 128) * 512 + e];
    Wp[i] = f2bf(val);
  } else if (bid < 1408) {
    int i = (bid - 384) * 256 + threadIdx.x;  // 512*512
    int m = i >> 9, n = i & 511;
    PEdT[i] = PE[n * 2048 + m * 2] * C_NORM_LOG2E;
    if (bid == 384 && threadIdx.x < 128) cnt[threadIdx.x] = 0u;
  } else {
    // odd-row zeros: 1M float4 over 1024 blocks x 256 thr x 4
    int zbid = bid - 1408;
#pragma unroll
    for (int k = 0; k < 4; ++k) {
      int z = zbid * 1024 + k * 256 + threadIdx.x;
      int b = z >> 17, zl = z & 131071;
      int row_o = zl >> 4, d4 = zl & 15;
      float* p = out + (size_t)b * 1048576 + (size_t)(2 * row_o + 1) * 64 + d4 * 4;
      *(float4*)p = (float4){0.f, 0.f, 0.f, 0.f};
    }
  }
}

// ---------------- projection: QKV[r][d] bf16, r = (b*16+s)*512 + m, from x[b, 32m+s, :] --------
__global__ __launch_bounds__(512, 4) void proj_kernel(
    const float* __restrict__ x, const ushort* __restrict__ Wp,
    ushort* __restrict__ Qw, ushort* __restrict__ Kw, ushort* __restrict__ Vw) {
  __shared__ float Xl[2][8192];  // 2 x 32KB: 128 rows x 64 f32, swizzled
  const int tid = threadIdx.x;
  const int lane = tid & 63, w = tid >> 6, g = lane >> 4, l15 = lane & 15;
  const int wr = w >> 2, wc = w & 3;  // 2x4 wave grid: 64 rows x 48 cols each
  const int bid = blockIdx.x;
  const int xcd = bid & 7, idx = bid >> 3;
  const int part = idx & 3, h = idx >> 2;
  const int bs = h * 8 + xcd;
  const int m0 = part * 128;
  const int R0 = bs * 512 + m0;
  const int b = bs >> 4, s = bs & 15;
  const char* xb = (const char*)x + ((size_t)b * 8388608 + (size_t)s * 512) * 4;

  f32x4 acc[4][3];
#pragma unroll
  for (int i = 0; i < 4; ++i)
#pragma unroll
    for (int j = 0; j < 3; ++j) acc[i][j] = (f32x4){0.f, 0.f, 0.f, 0.f};

  auto stage = [&](int kt, int buf) {
#pragma unroll
    for (int j = 0; j < 4; ++j) {
      uint32_t sl = (uint32_t)(j * 8192 + tid * 16);      // linear LDS byte slot
      uint32_t t = sl ^ (((sl >> 8) & 7u) << 4);          // pre-swizzled source index
      uint32_t row = t >> 8, colb = t & 255u;
      const char* src = xb + (size_t)(m0 + row) * 65536 + (size_t)kt * 256 + colb;
      gl_lds16(src, (char*)&Xl[buf][0] + sl);
    }
  };

  stage(0, 0);
  __syncthreads();
#pragma unroll
  for (int kt = 0; kt < 8; ++kt) {
    const int buf = kt & 1;
    if (kt < 7) stage(kt + 1, buf ^ 1);
#pragma unroll
    for (int kd = 0; kd < 2; ++kd) {
      bf16x8 bb[3];
#pragma unroll
      for (int j = 0; j < 3; ++j)
        bb[j] = *(const bf16x8*)((const char*)Wp + (size_t)(wc * 48 + j * 16 + l15) * 1024 +
                                 kt * 128 + kd * 64 + g * 16);
      bf16x8 a[4];
#pragma unroll
      for (int i = 0; i < 4; ++i) {
        int Rr = wr * 64 + i * 16 + l15;
        uint32_t a32 = (uint32_t)(Rr * 256 + kd * 128 + g * 32);
        uint32_t off0 = a32 ^ ((uint32_t)(Rr & 7) << 4);
        uint32_t off1 = off0 ^ 16u;
        f32x4 lo = *(const f32x4*)((const char*)&Xl[buf][0] + off0);
        f32x4 hi = *(const f32x4*)((const char*)&Xl[buf][0] + off1);
        uint32_t uu[4];
        uu[0] = cvt_pk_bf16(lo[0], lo[1]);
        uu[1] = cvt_pk_bf16(lo[2], lo[3]);
        uu[2] = cvt_pk_bf16(hi[0], hi[1]);
        uu[3] = cvt_pk_bf16(hi[2], hi[3]);
        a[i] = *(bf16x8*)uu;
      }
#pragma unroll
      for (int i = 0; i < 4; ++i)
#pragma unroll
        for (int j = 0; j < 3; ++j)
          acc[i][j] = __builtin_amdgcn_mfma_f32_16x16x32_bf16(a[i], bb[j], acc[i][j], 0, 0, 0);
    }
    __syncthreads();
  }
  // epilogue: D layout col = l15 (n), row = g*4 + r
#pragma unroll
  for (int i = 0; i < 4; ++i) {
    int rl2 = wr * 64 + i * 16 + g * 4;
    size_t rbase = (size_t)(R0 + rl2) * 64;
#pragma unroll
    for (int j = 0; j < 3; ++j) {
      int n = wc * 48 + j * 16 + l15;
      int sel = n >> 6, d = n & 63;
      ushort* dst = (sel == 0) ? Qw : (sel == 1) ? Kw : Vw;
      dst += rbase + d;
#pragma unroll
      for (int r = 0; r < 4; ++r) dst[(size_t)r * 64] = f2bf(acc[i][j][r]);
    }
  }
}

// ------- attention, chunked over n; last block per bs also reduces partials -> out -------
__global__ __launch_bounds__(512, 4) void attn_kernel(
    const ushort* __restrict__ Qw, const ushort* __restrict__ Kw,
    const ushort* __restrict__ Vw, const float* __restrict__ PEdT,
    ushort* __restrict__ Pp, unsigned* __restrict__ cnt, float* __restrict__ out) {
  __shared__ char Vtl[16384];   // 2 x [64 d][64 n] bf16 V^T tiles, swizzled
  __shared__ char Ptl[32768];   // per-wave 4KB: [64 m][32 n] bf16 half-tile, swizzled
  __shared__ float red[512];    // [wave][row]
  __shared__ float rZrow[64];
  __shared__ unsigned lastFlag;

  const int tid = threadIdx.x;
  const int w = tid >> 6, lane = tid & 63, g = lane >> 4, l15 = lane & 15;
  const int bid = blockIdx.x;
  const int xcd = bid & 7, idx = bid >> 3;
  const int bs = (idx & 15) * 8 + xcd;
  const int co = idx >> 4;
  const int c = co ^ (co >> 1);
  const int nmf = c + 1;           // 16-row m-fragments per wave
  const int wb = w * 16 * nmf;     // wave m-base
  const size_t base = (size_t)bs * 32768;
  const char* Qb = (const char*)(Qw + base);
  const char* Kb = (const char*)(Kw + base);
  const char* Vb = (const char*)(Vw + base);
  char* Pw = Ptl + w * 4096;

  const int vrow = tid >> 3, vseg = tid & 7;
  auto scatter = [&](uint4 d4, int buf) {
    uint32_t dwv[4] = {d4.x, d4.y, d4.z, d4.w};
#pragma unroll
    for (int t = 0; t < 4; ++t) {
      int d0 = vseg * 8 + t * 2;
      *(ushort*)(Vtl + buf * 8192 + swz((uint32_t)(d0 * 128 + vrow * 2))) = (ushort)(dwv[t] & 0xffffu);
      *(ushort*)(Vtl + buf * 8192 + swz((uint32_t)((d0 + 1) * 128 + vrow * 2))) = (ushort)(dwv[t] >> 16);
    }
  };

  uint4 dv = *(const uint4*)(Vb + (size_t)(2 * c) * 8192 + vrow * 128 + vseg * 16);
  scatter(dv, 0);
  dv = *(const uint4*)(Vb + (size_t)(2 * c + 1) * 8192 + vrow * 128 + vseg * 16);
  __syncthreads();  // B0: Vtl[0] ready

  f32x4 att[4][4];
#pragma unroll
  for (int i = 0; i < 4; ++i)
#pragma unroll
    for (int j = 0; j < 4; ++j) att[i][j] = (f32x4){0.f, 0.f, 0.f, 0.f};

#pragma unroll
  for (int it = 0; it < 2; ++it) {
    const int nt = 2 * c + it;
    if (it == 0) scatter(dv, 1);  // Vtl[1]; ordered vs reads by B2/B3 chain

    uint32_t Ppk2[2][4][2];  // nf=2,3 packed P held in regs
    float ls[4][4];
    // --- a: QK^T + bias/mask + exp2 + pack; nf<2 -> LDS half-tile, nf>=2 -> regs
#pragma unroll
    for (int nf = 0; nf < 4; ++nf) {
      bf16x8 aK[2];
#pragma unroll
      for (int kd = 0; kd < 2; ++kd)
        aK[kd] = *(const bf16x8*)(Kb + (size_t)nt * 8192 + (size_t)(nf * 16 + l15) * 128 +
                                  kd * 64 + g * 16);
      const int nb = nt * 64 + nf * 16 + g * 4;
      float l0 = 0.f, l1 = 0.f, l2 = 0.f, l3 = 0.f;
#pragma unroll
      for (int mf = 0; mf < 4; ++mf)
        if (mf < nmf) {
          const char* qrow = Qb + (size_t)(wb + mf * 16 + l15) * 128;
          bf16x8 q0 = *(const bf16x8*)(qrow + g * 16);
          bf16x8 q1 = *(const bf16x8*)(qrow + 64 + g * 16);
          f32x4 S = (f32x4){0.f, 0.f, 0.f, 0.f};
          S = __builtin_amdgcn_mfma_f32_16x16x32_bf16(aK[0], q0, S, 0, 0, 0);
          S = __builtin_amdgcn_mfma_f32_16x16x32_bf16(aK[1], q1, S, 0, 0, 0);
          int m_ = wb + mf * 16 + l15;
          f32x4 pe = *(const f32x4*)(PEdT + (size_t)m_ * 512 + nb);
          float e0 = (nb + 0 >= m_) ? exp2f(fmaf(S[0], C_NORM_LOG2E, pe[0])) : 0.f;
          float e1 = (nb + 1 >= m_) ? exp2f(fmaf(S[1], C_NORM_LOG2E, pe[1])) : 0.f;
          float e2 = (nb + 2 >= m_) ? exp2f(fmaf(S[2], C_NORM_LOG2E, pe[2])) : 0.f;
          float e3 = (nb + 3 >= m_) ? exp2f(fmaf(S[3], C_NORM_LOG2E, pe[3])) : 0.f;
          l0 += e0; l1 += e1; l2 += e2; l3 += e3;
          uint32_t ux = cvt_pk_bf16(e0, e1);
          uint32_t uy = cvt_pk_bf16(e2, e3);
          if (nf < 2) {
            uint2 u; u.x = ux; u.y = uy;
            *(uint2*)(Pw + swzP((uint32_t)((mf * 16 + l15) * 64 + (nf & 1) * 32 + g * 8))) = u;
          } else {
            Ppk2[nf - 2][mf][0] = ux;
            Ppk2[nf - 2][mf][1] = uy;
          }
        }
      ls[nf][0] = l0; ls[nf][1] = l1; ls[nf][2] = l2; ls[nf][3] = l3;
    }
    // --- b: butterfly over 16 lanes, stash per-wave partial Z
#pragma unroll
    for (int msk = 1; msk < 16; msk <<= 1)
#pragma unroll
      for (int nf = 0; nf < 4; ++nf)
#pragma unroll
        for (int r = 0; r < 4; ++r) ls[nf][r] += __shfl_xor(ls[nf][r], msk, 16);
    if (l15 == 0) {
#pragma unroll
      for (int nf = 0; nf < 4; ++nf)
#pragma unroll
        for (int r = 0; r < 4; ++r) red[w * 64 + nf * 16 + g * 4 + r] = ls[nf][r];
    }
    __syncthreads();  // B2
    // --- c: parallel rZ (wave w reduces rows 8w..8w+7)
    {
      int row8 = lane >> 3, srcw = lane & 7;
      float v = red[srcw * 64 + w * 8 + row8];
      v += __shfl_xor(v, 1);
      v += __shfl_xor(v, 2);
      v += __shfl_xor(v, 4);
      if (srcw == 0) rZrow[w * 8 + row8] = 1.0f / v;
    }
    __syncthreads();  // B3
    // --- d: PV with 1/Z folded into V fragments (rZ indexed by k-dim n)
#pragma unroll
    for (int kf = 0; kf < 2; ++kf) {
      if (kf == 1) {
#pragma unroll
        for (int nf2 = 0; nf2 < 2; ++nf2)
#pragma unroll
          for (int mf = 0; mf < 4; ++mf)
            if (mf < nmf) {
              uint2 u; u.x = Ppk2[nf2][mf][0]; u.y = Ppk2[nf2][mf][1];
              *(uint2*)(Pw + swzP((uint32_t)((mf * 16 + l15) * 64 + nf2 * 32 + g * 8))) = u;
            }
      }
      f32x4 za = *(const f32x4*)&rZrow[kf * 32 + g * 8];
      f32x4 zb = *(const f32x4*)&rZrow[kf * 32 + g * 8 + 4];
      bf16x8 bV[4];
#pragma unroll
      for (int df = 0; df < 4; ++df) {
        u32x4 vv = *(const u32x4*)(Vtl + it * 8192 +
                                   swz((uint32_t)((df * 16 + l15) * 128 + kf * 64 + g * 16)));
        uint32_t oo[4];
        float2 f0 = unpk_bf16(vv[0]);
        float2 f1 = unpk_bf16(vv[1]);
        float2 f2 = unpk_bf16(vv[2]);
        float2 f3 = unpk_bf16(vv[3]);
        oo[0] = cvt_pk_bf16(f0.x * za[0], f0.y * za[1]);
        oo[1] = cvt_pk_bf16(f1.x * za[2], f1.y * za[3]);
        oo[2] = cvt_pk_bf16(f2.x * zb[0], f2.y * zb[1]);
        oo[3] = cvt_pk_bf16(f3.x * zb[2], f3.y * zb[3]);
        bV[df] = *(bf16x8*)oo;
      }
#pragma unroll
      for (int mf = 0; mf < 4; ++mf)
        if (mf < nmf) {
          bf16x8 aP = *(const bf16x8*)(Pw + swzP((uint32_t)((mf * 16 + l15) * 64 + g * 16)));
#pragma unroll
          for (int df = 0; df < 4; ++df)
            att[mf][df] = __builtin_amdgcn_mfma_f32_16x16x32_bf16(aP, bV[df], att[mf][df], 0, 0, 0);
        }
    }
  }

  // epilogue: bf16 partial att^c at Pp[(c*128+bs)*32768 + m*64 + d]; rows m < 128*(c+1)
  ushort* pb = Pp + ((size_t)c * 128 + bs) * 32768;
#pragma unroll
  for (int mf = 0; mf < 4; ++mf)
    if (mf < nmf) {
#pragma unroll
      for (int df = 0; df < 4; ++df)
#pragma unroll
        for (int r = 0; r < 4; ++r) {
          int m_ = wb + mf * 16 + g * 4 + r;
          pb[(size_t)m_ * 64 + df * 16 + l15] = f2bf(att[mf][df][r]);
        }
    }

  // ---- last-block-per-bs fused reduction (deterministic: fixed cc sum order) ----
  __threadfence();   // release this block's partial writes to device scope
  __syncthreads();
  if (tid == 0) lastFlag = (atomicAdd(&cnt[bs], 1u) == 3u) ? 1u : 0u;
  __syncthreads();
  if (lastFlag == 0u) return;
  __threadfence();   // acquire: see all blocks' partials
  const int b = bs >> 4, s = bs & 15;
  float* obase = out + (size_t)b * 1048576 + (size_t)s * 65536;
#pragma unroll
  for (int k = 0; k < 8; ++k) {
    int jj = k * 512 + tid;
    int d8 = jj & 7, m = jj >> 3;
    const size_t ji = ((size_t)bs * 512 + m) * 64 + d8 * 8;
    float f[8];
#pragma unroll
    for (int e = 0; e < 8; ++e) f[e] = 0.f;
    for (int cc = m >> 7; cc < 4; ++cc) {  // chunk cc covers m < 128*(cc+1)
      uint4 v = *(const uint4*)(Pp + (size_t)cc * 4194304 + ji);
      uint32_t dw[4] = {v.x, v.y, v.z, v.w};
#pragma unroll
      for (int t = 0; t < 4; ++t) {
        f[t * 2] += __uint_as_float(dw[t] << 16);
        f[t * 2 + 1] += __uint_as_float(dw[t] & 0xffff0000u);
      }
    }
    float* ob = obase + (size_t)m * 128 + d8 * 8;   // even row 2*(s*512+m)
    *(float4*)(ob) = (float4){f[0], f[1], f[2], f[3]};
    *(float4*)(ob + 4) = (float4){f[4], f[5], f[6], f[7]};
  }
}

extern "C" void kernel_launch(void* const* d_in, const int* in_sizes, int n_in,
                              void* d_out, int out_size, void* d_ws, size_t ws_size,
                              hipStream_t stream) {
  const float* x  = (const float*)d_in[0];
  const float* Wk = (const float*)d_in[1];
  const float* Wq = (const float*)d_in[2];
  const float* Wv = (const float*)d_in[3];
  const float* PE = (const float*)d_in[4];
  float* out = (float*)d_out;
  char* ws = (char*)d_ws;

  ushort* Qw   = (ushort*)(ws);              // 8 MB
  ushort* Kw   = (ushort*)(ws + 8388608);    // 8 MB
  ushort* Vw   = (ushort*)(ws + 16777216);   // 8 MB
  ushort* Wp   = (ushort*)(ws + 25165824);   // 192 KB
  float*  PEdT = (float*)(ws + 25362432);    // 1 MB
  ushort* Pp   = (ushort*)(ws + 33554432);   // 32 MB partials (4 chunks)
  unsigned* cnt = (unsigned*)(ws + 67108864); // 512 B

  pack_kernel<<<dim3(2432), dim3(256), 0, stream>>>(Wk, Wq, Wv, PE, Wp, PEdT, cnt, out);
  proj_kernel<<<dim3(512), dim3(512), 0, stream>>>(x, Wp, Qw, Kw, Vw);
  attn_kernel<<<dim3(512), dim3(512), 0, stream>>>(Qw, Kw, Vw, PEdT, Pp, cnt, out);
}

// Round 7
// 129.987 us; speedup vs baseline: 2.1617x; 2.1617x over previous
//
#include <hip/hip_runtime.h>
#include <stdint.h>

typedef __attribute__((ext_vector_type(4))) float f32x4;
typedef __attribute__((ext_vector_type(8))) short bf16x8;
typedef __attribute__((ext_vector_type(4))) unsigned int u32x4;

#define C_NORM_LOG2E 0.18033688011112043f

// 128B-row swizzle (rows of 64 bf16 / 32 f32: XOR row&7 into byte bits 4-6)
__device__ __forceinline__ uint32_t swz(uint32_t a) { return a ^ (((a >> 7) & 7u) << 4); }
// 64B-row swizzle for the P half-tile (XOR (row>>1)&3 into bits 4-5; row-preserving)
__device__ __forceinline__ uint32_t swzP(uint32_t a) { return a ^ (((a >> 7) & 3u) << 4); }

__device__ __forceinline__ uint32_t cvt_pk_bf16(float a, float b) {
  uint32_t r;
  asm("v_cvt_pk_bf16_f32 %0, %1, %2" : "=v"(r) : "v"(a), "v"(b));
  return r;
}

__device__ __forceinline__ float2 unpk_bf16(uint32_t u) {
  float2 f;
  f.x = __uint_as_float(u << 16);
  f.y = __uint_as_float(u & 0xffff0000u);
  return f;
}

__device__ __forceinline__ ushort f2bf(float f) {
  uint32_t u = __float_as_uint(f);
  u += 0x7FFFu + ((u >> 16) & 1u);
  return (ushort)(u >> 16);
}

__device__ __forceinline__ void gl_lds16(const void* gp, void* lp) {
  __builtin_amdgcn_global_load_lds((const __attribute__((address_space(1))) void*)gp,
                                   (__attribute__((address_space(3))) void*)lp, 16, 0, 0);
}

// ---- pack: Wp [192][512] bf16 (Wq|Wk|Wv), PEdT[m][n] = PE[2n][2m]*NORM*log2e,
// ----       and zero all odd output rows (16 MB; BW-idle launch slot) ----
__global__ void pack_kernel(const float* __restrict__ Wk, const float* __restrict__ Wq,
                            const float* __restrict__ Wv, const float* __restrict__ PE,
                            ushort* __restrict__ Wp, float* __restrict__ PEdT,
                            float* __restrict__ out) {
  int bid = blockIdx.x;
  if (bid < 384) {
    int i = bid * 256 + threadIdx.x;  // 192*512
    int n = i >> 9, e = i & 511;
    float val = (n < 64) ? Wq[n * 512 + e]
              : (n < 128) ? Wk[(n - 64) * 512 + e]
                          : Wv[(n - 128) * 512 + e];
    Wp[i] = f2bf(val);
  } else if (bid < 1408) {
    int i = (bid - 384) * 256 + threadIdx.x;  // 512*512
    int m = i >> 9, n = i & 511;
    PEdT[i] = PE[n * 2048 + m * 2] * C_NORM_LOG2E;
  } else {
    // odd-row zeros: 1M float4 over 1024 blocks x 256 thr x 4
    int zbid = bid - 1408;
#pragma unroll
    for (int k = 0; k < 4; ++k) {
      int z = zbid * 1024 + k * 256 + threadIdx.x;
      int b = z >> 17, zl = z & 131071;
      int row_o = zl >> 4, d4 = zl & 15;
      float* p = out + (size_t)b * 1048576 + (size_t)(2 * row_o + 1) * 64 + d4 * 4;
      *(float4*)p = (float4){0.f, 0.f, 0.f, 0.f};
    }
  }
}

// ---------------- projection: QKV[r][d] bf16, r = (b*16+s)*512 + m, from x[b, 32m+s, :] --------
__global__ __launch_bounds__(512, 4) void proj_kernel(
    const float* __restrict__ x, const ushort* __restrict__ Wp,
    ushort* __restrict__ Qw, ushort* __restrict__ Kw, ushort* __restrict__ Vw) {
  __shared__ float Xl[2][8192];  // 2 x 32KB: 128 rows x 64 f32, swizzled
  const int tid = threadIdx.x;
  const int lane = tid & 63, w = tid >> 6, g = lane >> 4, l15 = lane & 15;
  const int wr = w >> 2, wc = w & 3;  // 2x4 wave grid: 64 rows x 48 cols each
  const int bid = blockIdx.x;
  const int xcd = bid & 7, idx = bid >> 3;
  const int part = idx & 3, h = idx >> 2;
  const int bs = h * 8 + xcd;
  const int m0 = part * 128;
  const int R0 = bs * 512 + m0;
  const int b = bs >> 4, s = bs & 15;
  const char* xb = (const char*)x + ((size_t)b * 8388608 + (size_t)s * 512) * 4;

  f32x4 acc[4][3];
#pragma unroll
  for (int i = 0; i < 4; ++i)
#pragma unroll
    for (int j = 0; j < 3; ++j) acc[i][j] = (f32x4){0.f, 0.f, 0.f, 0.f};

  auto stage = [&](int kt, int buf) {
#pragma unroll
    for (int j = 0; j < 4; ++j) {
      uint32_t sl = (uint32_t)(j * 8192 + tid * 16);      // linear LDS byte slot
      uint32_t t = sl ^ (((sl >> 8) & 7u) << 4);          // pre-swizzled source index
      uint32_t row = t >> 8, colb = t & 255u;
      const char* src = xb + (size_t)(m0 + row) * 65536 + (size_t)kt * 256 + colb;
      gl_lds16(src, (char*)&Xl[buf][0] + sl);
    }
  };

  stage(0, 0);
  __syncthreads();
#pragma unroll
  for (int kt = 0; kt < 8; ++kt) {
    const int buf = kt & 1;
    if (kt < 7) stage(kt + 1, buf ^ 1);
#pragma unroll
    for (int kd = 0; kd < 2; ++kd) {
      bf16x8 bb[3];
#pragma unroll
      for (int j = 0; j < 3; ++j)
        bb[j] = *(const bf16x8*)((const char*)Wp + (size_t)(wc * 48 + j * 16 + l15) * 1024 +
                                 kt * 128 + kd * 64 + g * 16);
      bf16x8 a[4];
#pragma unroll
      for (int i = 0; i < 4; ++i) {
        int Rr = wr * 64 + i * 16 + l15;
        uint32_t a32 = (uint32_t)(Rr * 256 + kd * 128 + g * 32);
        uint32_t off0 = a32 ^ ((uint32_t)(Rr & 7) << 4);
        uint32_t off1 = off0 ^ 16u;
        f32x4 lo = *(const f32x4*)((const char*)&Xl[buf][0] + off0);
        f32x4 hi = *(const f32x4*)((const char*)&Xl[buf][0] + off1);
        uint32_t uu[4];
        uu[0] = cvt_pk_bf16(lo[0], lo[1]);
        uu[1] = cvt_pk_bf16(lo[2], lo[3]);
        uu[2] = cvt_pk_bf16(hi[0], hi[1]);
        uu[3] = cvt_pk_bf16(hi[2], hi[3]);
        a[i] = *(bf16x8*)uu;
      }
#pragma unroll
      for (int i = 0; i < 4; ++i)
#pragma unroll
        for (int j = 0; j < 3; ++j)
          acc[i][j] = __builtin_amdgcn_mfma_f32_16x16x32_bf16(a[i], bb[j], acc[i][j], 0, 0, 0);
    }
    __syncthreads();
  }
  // epilogue: D layout col = l15 (n), row = g*4 + r
#pragma unroll
  for (int i = 0; i < 4; ++i) {
    int rl2 = wr * 64 + i * 16 + g * 4;
    size_t rbase = (size_t)(R0 + rl2) * 64;
#pragma unroll
    for (int j = 0; j < 3; ++j) {
      int n = wc * 48 + j * 16 + l15;
      int sel = n >> 6, d = n & 63;
      ushort* dst = (sel == 0) ? Qw : (sel == 1) ? Kw : Vw;
      dst += rbase + d;
#pragma unroll
      for (int r = 0; r < 4; ++r) dst[(size_t)r * 64] = f2bf(acc[i][j][r]);
    }
  }
}

// ------- attention, chunked over n: block = (bs, c), rows n in [128c,128c+128) -------
// Balanced waves (wave w: m in [w*16*(c+1), ...)). No-max softmax. 1/Z folded into V frags.
__global__ __launch_bounds__(512, 4) void attn_kernel(
    const ushort* __restrict__ Qw, const ushort* __restrict__ Kw,
    const ushort* __restrict__ Vw, const float* __restrict__ PEdT,
    ushort* __restrict__ Pp) {
  __shared__ char Vtl[16384];   // 2 x [64 d][64 n] bf16 V^T tiles, swizzled
  __shared__ char Ptl[32768];   // per-wave 4KB: [64 m][32 n] bf16 half-tile, swizzled
  __shared__ float red[512];    // [wave][row]
  __shared__ float rZrow[64];

  const int tid = threadIdx.x;
  const int w = tid >> 6, lane = tid & 63, g = lane >> 4, l15 = lane & 15;
  const int bid = blockIdx.x;
  const int xcd = bid & 7, idx = bid >> 3;
  const int bs = (idx & 15) * 8 + xcd;
  const int co = idx >> 4;
  const int c = co ^ (co >> 1);
  const int nmf = c + 1;           // 16-row m-fragments per wave
  const int wb = w * 16 * nmf;     // wave m-base
  const size_t base = (size_t)bs * 32768;
  const char* Qb = (const char*)(Qw + base);
  const char* Kb = (const char*)(Kw + base);
  const char* Vb = (const char*)(Vw + base);
  char* Pw = Ptl + w * 4096;

  const int vrow = tid >> 3, vseg = tid & 7;
  auto scatter = [&](uint4 d4, int buf) {
    uint32_t dwv[4] = {d4.x, d4.y, d4.z, d4.w};
#pragma unroll
    for (int t = 0; t < 4; ++t) {
      int d0 = vseg * 8 + t * 2;
      *(ushort*)(Vtl + buf * 8192 + swz((uint32_t)(d0 * 128 + vrow * 2))) = (ushort)(dwv[t] & 0xffffu);
      *(ushort*)(Vtl + buf * 8192 + swz((uint32_t)((d0 + 1) * 128 + vrow * 2))) = (ushort)(dwv[t] >> 16);
    }
  };

  uint4 dv = *(const uint4*)(Vb + (size_t)(2 * c) * 8192 + vrow * 128 + vseg * 16);
  scatter(dv, 0);
  dv = *(const uint4*)(Vb + (size_t)(2 * c + 1) * 8192 + vrow * 128 + vseg * 16);

  // persistent Q fragments for this wave's m-slice (<=32 VGPR)
  bf16x8 bQ[4][2];
#pragma unroll
  for (int mf = 0; mf < 4; ++mf)
    if (mf < nmf) {
      const char* qrow = Qb + (size_t)(wb + mf * 16 + l15) * 128;
      bQ[mf][0] = *(const bf16x8*)(qrow + g * 16);
      bQ[mf][1] = *(const bf16x8*)(qrow + 64 + g * 16);
    }
  __syncthreads();  // B0: Vtl[0] ready

  f32x4 att[4][4];
#pragma unroll
  for (int i = 0; i < 4; ++i)
#pragma unroll
    for (int j = 0; j < 4; ++j) att[i][j] = (f32x4){0.f, 0.f, 0.f, 0.f};

#pragma unroll
  for (int it = 0; it < 2; ++it) {
    const int nt = 2 * c + it;
    if (it == 0) scatter(dv, 1);  // Vtl[1]; ordered vs reads by B2/B3 chain

    uint32_t Ppk2[2][4][2];  // nf=2,3 packed P held in regs
    float ls[4][4];
    // --- a: QK^T + bias/mask + exp2 + pack; nf<2 -> LDS half-tile, nf>=2 -> regs
#pragma unroll
    for (int nf = 0; nf < 4; ++nf) {
      bf16x8 aK[2];
#pragma unroll
      for (int kd = 0; kd < 2; ++kd)
        aK[kd] = *(const bf16x8*)(Kb + (size_t)nt * 8192 + (size_t)(nf * 16 + l15) * 128 +
                                  kd * 64 + g * 16);
      const int nb = nt * 64 + nf * 16 + g * 4;
      float l0 = 0.f, l1 = 0.f, l2 = 0.f, l3 = 0.f;
#pragma unroll
      for (int mf = 0; mf < 4; ++mf)
        if (mf < nmf) {
          f32x4 S = (f32x4){0.f, 0.f, 0.f, 0.f};
          S = __builtin_amdgcn_mfma_f32_16x16x32_bf16(aK[0], bQ[mf][0], S, 0, 0, 0);
          S = __builtin_amdgcn_mfma_f32_16x16x32_bf16(aK[1], bQ[mf][1], S, 0, 0, 0);
          int m_ = wb + mf * 16 + l15;
          f32x4 pe = *(const f32x4*)(PEdT + (size_t)m_ * 512 + nb);
          float e0 = (nb + 0 >= m_) ? exp2f(fmaf(S[0], C_NORM_LOG2E, pe[0])) : 0.f;
          float e1 = (nb + 1 >= m_) ? exp2f(fmaf(S[1], C_NORM_LOG2E, pe[1])) : 0.f;
          float e2 = (nb + 2 >= m_) ? exp2f(fmaf(S[2], C_NORM_LOG2E, pe[2])) : 0.f;
          float e3 = (nb + 3 >= m_) ? exp2f(fmaf(S[3], C_NORM_LOG2E, pe[3])) : 0.f;
          l0 += e0; l1 += e1; l2 += e2; l3 += e3;
          uint32_t ux = cvt_pk_bf16(e0, e1);
          uint32_t uy = cvt_pk_bf16(e2, e3);
          if (nf < 2) {
            uint2 u; u.x = ux; u.y = uy;
            *(uint2*)(Pw + swzP((uint32_t)((mf * 16 + l15) * 64 + (nf & 1) * 32 + g * 8))) = u;
          } else {
            Ppk2[nf - 2][mf][0] = ux;
            Ppk2[nf - 2][mf][1] = uy;
          }
        }
      ls[nf][0] = l0; ls[nf][1] = l1; ls[nf][2] = l2; ls[nf][3] = l3;
    }
    // --- b: butterfly over 16 lanes, stash per-wave partial Z
#pragma unroll
    for (int msk = 1; msk < 16; msk <<= 1)
#pragma unroll
      for (int nf = 0; nf < 4; ++nf)
#pragma unroll
        for (int r = 0; r < 4; ++r) ls[nf][r] += __shfl_xor(ls[nf][r], msk, 16);
    if (l15 == 0) {
#pragma unroll
      for (int nf = 0; nf < 4; ++nf)
#pragma unroll
        for (int r = 0; r < 4; ++r) red[w * 64 + nf * 16 + g * 4 + r] = ls[nf][r];
    }
    __syncthreads();  // B2
    // --- c: parallel rZ (wave w reduces rows 8w..8w+7)
    {
      int row8 = lane >> 3, srcw = lane & 7;
      float v = red[srcw * 64 + w * 8 + row8];
      v += __shfl_xor(v, 1);
      v += __shfl_xor(v, 2);
      v += __shfl_xor(v, 4);
      if (srcw == 0) rZrow[w * 8 + row8] = 1.0f / v;
    }
    __syncthreads();  // B3
    // --- d: PV with 1/Z folded into V fragments (rZ indexed by k-dim n)
#pragma unroll
    for (int kf = 0; kf < 2; ++kf) {
      if (kf == 1) {
#pragma unroll
        for (int nf2 = 0; nf2 < 2; ++nf2)
#pragma unroll
          for (int mf = 0; mf < 4; ++mf)
            if (mf < nmf) {
              uint2 u; u.x = Ppk2[nf2][mf][0]; u.y = Ppk2[nf2][mf][1];
              *(uint2*)(Pw + swzP((uint32_t)((mf * 16 + l15) * 64 + nf2 * 32 + g * 8))) = u;
            }
      }
      f32x4 za = *(const f32x4*)&rZrow[kf * 32 + g * 8];
      f32x4 zb = *(const f32x4*)&rZrow[kf * 32 + g * 8 + 4];
      bf16x8 bV[4];
#pragma unroll
      for (int df = 0; df < 4; ++df) {
        u32x4 vv = *(const u32x4*)(Vtl + it * 8192 +
                                   swz((uint32_t)((df * 16 + l15) * 128 + kf * 64 + g * 16)));
        uint32_t oo[4];
        float2 f0 = unpk_bf16(vv[0]);
        float2 f1 = unpk_bf16(vv[1]);
        float2 f2 = unpk_bf16(vv[2]);
        float2 f3 = unpk_bf16(vv[3]);
        oo[0] = cvt_pk_bf16(f0.x * za[0], f0.y * za[1]);
        oo[1] = cvt_pk_bf16(f1.x * za[2], f1.y * za[3]);
        oo[2] = cvt_pk_bf16(f2.x * zb[0], f2.y * zb[1]);
        oo[3] = cvt_pk_bf16(f3.x * zb[2], f3.y * zb[3]);
        bV[df] = *(bf16x8*)oo;
      }
#pragma unroll
      for (int mf = 0; mf < 4; ++mf)
        if (mf < nmf) {
          bf16x8 aP = *(const bf16x8*)(Pw + swzP((uint32_t)((mf * 16 + l15) * 64 + g * 16)));
#pragma unroll
          for (int df = 0; df < 4; ++df)
            att[mf][df] = __builtin_amdgcn_mfma_f32_16x16x32_bf16(aP, bV[df], att[mf][df], 0, 0, 0);
        }
    }
  }

  // epilogue: bf16 partial att^c at Pp[(c*128+bs)*32768 + m*64 + d]; rows m < 128*(c+1)
  ushort* pb = Pp + ((size_t)c * 128 + bs) * 32768;
#pragma unroll
  for (int mf = 0; mf < 4; ++mf)
    if (mf < nmf) {
#pragma unroll
      for (int df = 0; df < 4; ++df)
#pragma unroll
        for (int r = 0; r < 4; ++r) {
          int m_ = wb + mf * 16 + g * 4 + r;
          pb[(size_t)m_ * 64 + df * 16 + l15] = f2bf(att[mf][df][r]);
        }
    }
}

// ---------------- reduce: out[b,2m',d] = sum over valid chunks (even rows only) ----------------
__global__ void reduce_kernel(const ushort* __restrict__ Pp, float* __restrict__ out) {
  // XCD swizzle: blocks for segment bs land on XCD bs%8 (same L2 as attn partial writes)
  const int bid = blockIdx.x;
  const int xcd = bid & 7, idx = bid >> 3;
  const int bs = (idx & 15) * 8 + xcd;
  const int inner = idx >> 4;
  int jj = bs * 4096 + inner * 256 + threadIdx.x;
  int d8 = jj & 7, m = (jj >> 3) & 511;
  const size_t ji = ((size_t)bs * 512 + m) * 64 + d8 * 8;
  float f[8];
#pragma unroll
  for (int e = 0; e < 8; ++e) f[e] = 0.f;
  for (int cc = m >> 7; cc < 4; ++cc) {  // chunk cc covers m < 128*(cc+1)
    uint4 v = *(const uint4*)(Pp + (size_t)cc * 4194304 + ji);
    uint32_t dw[4] = {v.x, v.y, v.z, v.w};
#pragma unroll
    for (int t = 0; t < 4; ++t) {
      f[t * 2] += __uint_as_float(dw[t] << 16);
      f[t * 2 + 1] += __uint_as_float(dw[t] & 0xffff0000u);
    }
  }
  int b = bs >> 4, s = bs & 15;
  size_t t0 = 2 * ((size_t)s * 512 + m);
  float* ob = out + (size_t)b * 1048576 + t0 * 64 + d8 * 8;
  *(float4*)(ob) = (float4){f[0], f[1], f[2], f[3]};
  *(float4*)(ob + 4) = (float4){f[4], f[5], f[6], f[7]};
}

extern "C" void kernel_launch(void* const* d_in, const int* in_sizes, int n_in,
                              void* d_out, int out_size, void* d_ws, size_t ws_size,
                              hipStream_t stream) {
  const float* x  = (const float*)d_in[0];
  const float* Wk = (const float*)d_in[1];
  const float* Wq = (const float*)d_in[2];
  const float* Wv = (const float*)d_in[3];
  const float* PE = (const float*)d_in[4];
  float* out = (float*)d_out;
  char* ws = (char*)d_ws;

  ushort* Qw   = (ushort*)(ws);              // 8 MB
  ushort* Kw   = (ushort*)(ws + 8388608);    // 8 MB
  ushort* Vw   = (ushort*)(ws + 16777216);   // 8 MB
  ushort* Wp   = (ushort*)(ws + 25165824);   // 192 KB
  float*  PEdT = (float*)(ws + 25362432);    // 1 MB
  ushort* Pp   = (ushort*)(ws + 33554432);   // 32 MB partials (4 chunks)

  pack_kernel<<<dim3(2432), dim3(256), 0, stream>>>(Wk, Wq, Wv, PE, Wp, PEdT, out);
  proj_kernel<<<dim3(512), dim3(512), 0, stream>>>(x, Wp, Qw, Kw, Vw);
  attn_kernel<<<dim3(512), dim3(512), 0, stream>>>(Qw, Kw, Vw, PEdT, Pp);
  reduce_kernel<<<dim3(2048), dim3(256), 0, stream>>>(Pp, out);
}

// Round 8
// 101.060 us; speedup vs baseline: 2.7804x; 1.2862x over previous
//
#include <hip/hip_runtime.h>
#include <stdint.h>

typedef __attribute__((ext_vector_type(4))) float f32x4;
typedef __attribute__((ext_vector_type(8))) short bf16x8;

#define C_NORM_LOG2E 0.18033688011112043f

// 128B-row swizzle: XOR row&7 (addr bits 7-9) into byte bits 4-6
__device__ __forceinline__ uint32_t swz(uint32_t a) { return a ^ (((a >> 7) & 7u) << 4); }

__device__ __forceinline__ uint32_t cvt_pk_bf16(float a, float b) {
  uint32_t r;
  asm("v_cvt_pk_bf16_f32 %0, %1, %2" : "=v"(r) : "v"(a), "v"(b));
  return r;
}

__device__ __forceinline__ ushort f2bf(float f) {
  uint32_t u = __float_as_uint(f);
  u += 0x7FFFu + ((u >> 16) & 1u);
  return (ushort)(u >> 16);
}

__device__ __forceinline__ void gl_lds16(const void* gp, void* lp) {
  __builtin_amdgcn_global_load_lds((const __attribute__((address_space(1))) void*)gp,
                                   (__attribute__((address_space(3))) void*)lp, 16, 0, 0);
}

// ---- pack: Wp [192][512] bf16 (Wq|Wk|Wv) and PEdT[m][n] = PE[2n][2m]*NORM*log2e ----
__global__ void pack_kernel(const float* __restrict__ Wk, const float* __restrict__ Wq,
                            const float* __restrict__ Wv, const float* __restrict__ PE,
                            ushort* __restrict__ Wp, float* __restrict__ PEdT) {
  int bid = blockIdx.x;
  if (bid < 384) {
    int i = bid * 256 + threadIdx.x;  // 192*512
    int n = i >> 9, e = i & 511;
    float val = (n < 64) ? Wq[n * 512 + e]
              : (n < 128) ? Wk[(n - 64) * 512 + e]
                          : Wv[(n - 128) * 512 + e];
    Wp[i] = f2bf(val);
  } else {
    int i = (bid - 384) * 256 + threadIdx.x;  // 512*512
    int m = i >> 9, n = i & 511;
    PEdT[i] = PE[n * 2048 + m * 2] * C_NORM_LOG2E;
  }
}

// ---------------- projection: QKV[r][d] bf16, r = (b*16+s)*512 + m, from x[b, 32m+s, :] --------
__global__ __launch_bounds__(512, 4) void proj_kernel(
    const float* __restrict__ x, const ushort* __restrict__ Wp,
    ushort* __restrict__ Qw, ushort* __restrict__ Kw, ushort* __restrict__ Vw) {
  __shared__ float Xl[2][8192];  // 2 x 32KB: 128 rows x 64 f32, swizzled (256B rows)
  const int tid = threadIdx.x;
  const int lane = tid & 63, w = tid >> 6, g = lane >> 4, l15 = lane & 15;
  const int wr = w >> 2, wc = w & 3;  // 2x4 wave grid: 64 rows x 48 cols each
  const int bid = blockIdx.x;
  const int xcd = bid & 7, idx = bid >> 3;
  const int part = idx & 3, h = idx >> 2;
  const int bs = h * 8 + xcd;
  const int m0 = part * 128;
  const int R0 = bs * 512 + m0;
  const int b = bs >> 4, s = bs & 15;
  const char* xb = (const char*)x + ((size_t)b * 8388608 + (size_t)s * 512) * 4;

  f32x4 acc[4][3];
#pragma unroll
  for (int i = 0; i < 4; ++i)
#pragma unroll
    for (int j = 0; j < 3; ++j) acc[i][j] = (f32x4){0.f, 0.f, 0.f, 0.f};

  auto stage = [&](int kt, int buf) {
#pragma unroll
    for (int j = 0; j < 4; ++j) {
      uint32_t sl = (uint32_t)(j * 8192 + tid * 16);      // linear LDS byte slot
      uint32_t t = sl ^ (((sl >> 8) & 7u) << 4);          // pre-swizzled source index
      uint32_t row = t >> 8, colb = t & 255u;
      const char* src = xb + (size_t)(m0 + row) * 65536 + (size_t)kt * 256 + colb;
      gl_lds16(src, (char*)&Xl[buf][0] + sl);
    }
  };

  stage(0, 0);
  __syncthreads();
#pragma unroll
  for (int kt = 0; kt < 8; ++kt) {
    const int buf = kt & 1;
    if (kt < 7) stage(kt + 1, buf ^ 1);
#pragma unroll
    for (int kd = 0; kd < 2; ++kd) {
      bf16x8 bb[3];
#pragma unroll
      for (int j = 0; j < 3; ++j)
        bb[j] = *(const bf16x8*)((const char*)Wp + (size_t)(wc * 48 + j * 16 + l15) * 1024 +
                                 kt * 128 + kd * 64 + g * 16);
      bf16x8 a[4];
#pragma unroll
      for (int i = 0; i < 4; ++i) {
        int Rr = wr * 64 + i * 16 + l15;
        uint32_t a32 = (uint32_t)(Rr * 256 + kd * 128 + g * 32);
        uint32_t off0 = a32 ^ ((uint32_t)(Rr & 7) << 4);
        uint32_t off1 = off0 ^ 16u;
        f32x4 lo = *(const f32x4*)((const char*)&Xl[buf][0] + off0);
        f32x4 hi = *(const f32x4*)((const char*)&Xl[buf][0] + off1);
        uint32_t uu[4];
        uu[0] = cvt_pk_bf16(lo[0], lo[1]);
        uu[1] = cvt_pk_bf16(lo[2], lo[3]);
        uu[2] = cvt_pk_bf16(hi[0], hi[1]);
        uu[3] = cvt_pk_bf16(hi[2], hi[3]);
        a[i] = *(bf16x8*)uu;
      }
#pragma unroll
      for (int i = 0; i < 4; ++i)
#pragma unroll
        for (int j = 0; j < 3; ++j)
          acc[i][j] = __builtin_amdgcn_mfma_f32_16x16x32_bf16(a[i], bb[j], acc[i][j], 0, 0, 0);
    }
    __syncthreads();
  }
#pragma unroll
  for (int i = 0; i < 4; ++i) {
    int rl2 = wr * 64 + i * 16 + g * 4;
    size_t rbase = (size_t)(R0 + rl2) * 64;
#pragma unroll
    for (int j = 0; j < 3; ++j) {
      int n = wc * 48 + j * 16 + l15;
      int sel = n >> 6, d = n & 63;
      ushort* dst = (sel == 0) ? Qw : (sel == 1) ? Kw : Vw;
      dst += rbase + d;
#pragma unroll
      for (int r = 0; r < 4; ++r) dst[(size_t)r * 64] = f2bf(acc[i][j][r]);
    }
  }
}

// ---- zrec: block (bs, nc) computes rZ[bs, n] = 1/sum_m exp(...) for n in [nc*128, +128) ----
// ---- also zeroes the odd output rows of this quarter (spare BW). Q m-tiles LDS-staged. ----
__global__ __launch_bounds__(512, 4) void zrec_kernel(
    const ushort* __restrict__ Qw, const ushort* __restrict__ Kw,
    const float* __restrict__ PEdT, float* __restrict__ rZ,
    float* __restrict__ out) {
  __shared__ char Ql[2][8192];  // 64 m-rows x 64 d bf16, swizzled
  const int tid = threadIdx.x;
  const int w = tid >> 6, lane = tid & 63, g = lane >> 4, l15 = lane & 15;
  const int bid = blockIdx.x;
  const int hi = bid >> 8, lo = bid & 255;
  const int half = lo >> 7, bs = lo & 127;
  const int nc = (hi << 1) | (half ^ hi);  // co-resident pairs (0,3),(1,2): equal work
  const int b = bs >> 4, s = bs & 15;

  // odd-row zeros for m' in [nc*128, nc*128+128)
  {
    float* ob = out + (size_t)b * 1048576;
#pragma unroll
    for (int k = 0; k < 4; ++k) {
      int jj = k * 512 + tid;
      int rowl = jj >> 4, d4 = jj & 15;
      int mrow = nc * 128 + rowl;
      float* p = ob + (size_t)(2 * (s * 512 + mrow) + 1) * 64 + d4 * 4;
      *(float4*)p = (float4){0.f, 0.f, 0.f, 0.f};
    }
  }

  const char* Qb = (const char*)(Qw + (size_t)bs * 32768);
  const char* Kb = (const char*)(Kw + (size_t)bs * 32768);
  const int nw0 = nc * 128 + w * 16;  // wave's 16 n-rows
  bf16x8 aK0, aK1;
  {
    const char* kr = Kb + (size_t)(nw0 + l15) * 128;
    aK0 = *(const bf16x8*)(kr + g * 16);
    aK1 = *(const bf16x8*)(kr + 64 + g * 16);
  }
  const int NT = 2 * (nc + 1);  // m-tiles of 64 covering m <= nc*128+127
  auto stage = [&](int mt, int buf) {
    uint32_t sl = (uint32_t)(tid * 16);
    uint32_t t = sl ^ (((sl >> 7) & 7u) << 4);  // pre-swizzled source
    uint32_t row = t >> 7, colb = t & 127u;
    gl_lds16(Qb + (size_t)(mt * 64 + row) * 128 + colb, (char*)&Ql[buf][0] + sl);
  };
  stage(0, 0);
  float z0 = 0.f, z1 = 0.f, z2 = 0.f, z3 = 0.f;
  __syncthreads();
  for (int mt = 0; mt < NT; ++mt) {
    const int buf = mt & 1;
    if (mt + 1 < NT) stage(mt + 1, buf ^ 1);
    if (mt * 64 <= nw0 + 15) {  // tiles entirely above the diagonal are all-masked
#pragma unroll
      for (int mf = 0; mf < 4; ++mf) {
        int mq = mf * 16 + l15;
        bf16x8 q0 = *(const bf16x8*)((char*)&Ql[buf][0] + swz((uint32_t)(mq * 128 + g * 16)));
        bf16x8 q1 = *(const bf16x8*)((char*)&Ql[buf][0] + swz((uint32_t)(mq * 128 + 64 + g * 16)));
        f32x4 S = (f32x4){0.f, 0.f, 0.f, 0.f};
        S = __builtin_amdgcn_mfma_f32_16x16x32_bf16(aK0, q0, S, 0, 0, 0);
        S = __builtin_amdgcn_mfma_f32_16x16x32_bf16(aK1, q1, S, 0, 0, 0);
        int m_ = mt * 64 + mq;
        f32x4 pe = *(const f32x4*)(PEdT + (size_t)m_ * 512 + nw0 + g * 4);
        int nr = nw0 + g * 4;
        if (nr + 0 >= m_) z0 += exp2f(fmaf(S[0], C_NORM_LOG2E, pe[0]));
        if (nr + 1 >= m_) z1 += exp2f(fmaf(S[1], C_NORM_LOG2E, pe[1]));
        if (nr + 2 >= m_) z2 += exp2f(fmaf(S[2], C_NORM_LOG2E, pe[2]));
        if (nr + 3 >= m_) z3 += exp2f(fmaf(S[3], C_NORM_LOG2E, pe[3]));
      }
    }
    __syncthreads();
  }
#pragma unroll
  for (int msk = 1; msk < 16; msk <<= 1) {
    z0 += __shfl_xor(z0, msk, 16);
    z1 += __shfl_xor(z1, msk, 16);
    z2 += __shfl_xor(z2, msk, 16);
    z3 += __shfl_xor(z3, msk, 16);
  }
  if (l15 == 0) {
    float* zp = rZ + (size_t)bs * 512 + nw0 + g * 4;
    zp[0] = 1.0f / z0;
    zp[1] = 1.0f / z1;
    zp[2] = 1.0f / z2;
    zp[3] = 1.0f / z3;
  }
}

// ---- attn: block (bs, ms) owns output rows m in [ms*128, +128); per wave 16 m-rows. ----
// ---- P normalized at exp time via precomputed rZ[n]; f32 acc over all n; direct out. ----
__global__ __launch_bounds__(512, 4) void attn_kernel(
    const ushort* __restrict__ Qw, const ushort* __restrict__ Kw,
    const ushort* __restrict__ Vw, const float* __restrict__ PEdT,
    const float* __restrict__ rZ, float* __restrict__ out) {
  __shared__ char Vtl[2][8192];  // V^T tile [64 d][64 n] bf16, swizzled
  __shared__ char Ptl[8][2048];  // per-wave P^T [16 m][64 n] bf16, swizzled

  const int tid = threadIdx.x;
  const int w = tid >> 6, lane = tid & 63, g = lane >> 4, l15 = lane & 15;
  const int bid = blockIdx.x;
  const int hi = bid >> 8, lo = bid & 255;
  const int half = lo >> 7, bs = lo & 127;
  const int ms = (hi << 1) | (half ^ hi);  // co-resident pairs (0,3),(1,2): 8+2 / 6+4 tiles
  const int m0w = ms * 128 + w * 16;       // wave's m base
  const size_t base = (size_t)bs * 32768;
  const char* Qb = (const char*)(Qw + base);
  const char* Kb = (const char*)(Kw + base);
  const char* Vb = (const char*)(Vw + base);
  char* Pw = &Ptl[w][0];

  // persistent Q fragment (16 m-cols)
  bf16x8 bQ0, bQ1;
  {
    const char* qr = Qb + (size_t)(m0w + l15) * 128;
    bQ0 = *(const bf16x8*)(qr + g * 16);
    bQ1 = *(const bf16x8*)(qr + 64 + g * 16);
  }

  f32x4 acc[4];
#pragma unroll
  for (int j = 0; j < 4; ++j) acc[j] = (f32x4){0.f, 0.f, 0.f, 0.f};

  const int t0 = 2 * ms, NTT = 8 - t0;  // n-tiles t0..7 (below-diagonal skipped)
  const int vrow = tid >> 3, vseg = tid & 7;
  auto scatter = [&](uint4 d4, int buf) {
    uint32_t dwv[4] = {d4.x, d4.y, d4.z, d4.w};
#pragma unroll
    for (int t = 0; t < 4; ++t) {
      int d0 = vseg * 8 + t * 2;
      *(ushort*)(&Vtl[buf][0] + swz((uint32_t)(d0 * 128 + vrow * 2))) = (ushort)(dwv[t] & 0xffffu);
      *(ushort*)(&Vtl[buf][0] + swz((uint32_t)((d0 + 1) * 128 + vrow * 2))) = (ushort)(dwv[t] >> 16);
    }
  };

  uint4 dv = *(const uint4*)(Vb + (size_t)t0 * 8192 + vrow * 128 + vseg * 16);
  scatter(dv, 0);
  if (NTT > 1) dv = *(const uint4*)(Vb + (size_t)(t0 + 1) * 8192 + vrow * 128 + vseg * 16);
  __syncthreads();

  for (int tt = 0; tt < NTT; ++tt) {
    const int t = t0 + tt, buf = tt & 1;
    if (tt + 1 < NTT) {
      scatter(dv, buf ^ 1);
      if (tt + 2 < NTT)
        dv = *(const uint4*)(Vb + (size_t)(t + 2) * 8192 + vrow * 128 + vseg * 16);
    }
    const bool wact = (m0w <= t * 64 + 63);  // diagonal-tile wave skip
    if (wact) {
      const int m_ = m0w + l15;
#pragma unroll
      for (int nf = 0; nf < 4; ++nf) {
        const char* kr = Kb + (size_t)t * 8192 + (size_t)(nf * 16 + l15) * 128;
        bf16x8 k0 = *(const bf16x8*)(kr + g * 16);
        bf16x8 k1 = *(const bf16x8*)(kr + 64 + g * 16);
        f32x4 S = (f32x4){0.f, 0.f, 0.f, 0.f};
        S = __builtin_amdgcn_mfma_f32_16x16x32_bf16(k0, bQ0, S, 0, 0, 0);
        S = __builtin_amdgcn_mfma_f32_16x16x32_bf16(k1, bQ1, S, 0, 0, 0);
        const int nb = t * 64 + nf * 16 + g * 4;
        f32x4 pe = *(const f32x4*)(PEdT + (size_t)m_ * 512 + nb);
        f32x4 rz4 = *(const f32x4*)(rZ + (size_t)bs * 512 + nb);
        float e0 = (nb + 0 >= m_) ? exp2f(fmaf(S[0], C_NORM_LOG2E, pe[0])) * rz4[0] : 0.f;
        float e1 = (nb + 1 >= m_) ? exp2f(fmaf(S[1], C_NORM_LOG2E, pe[1])) * rz4[1] : 0.f;
        float e2 = (nb + 2 >= m_) ? exp2f(fmaf(S[2], C_NORM_LOG2E, pe[2])) * rz4[2] : 0.f;
        float e3 = (nb + 3 >= m_) ? exp2f(fmaf(S[3], C_NORM_LOG2E, pe[3])) * rz4[3] : 0.f;
        uint2 u;
        u.x = cvt_pk_bf16(e0, e1);
        u.y = cvt_pk_bf16(e2, e3);
        *(uint2*)(Pw + swz((uint32_t)(l15 * 128 + nf * 32 + g * 8))) = u;
      }
#pragma unroll
      for (int kf = 0; kf < 2; ++kf) {
        bf16x8 aP = *(const bf16x8*)(Pw + swz((uint32_t)(l15 * 128 + kf * 64 + g * 16)));
#pragma unroll
        for (int df = 0; df < 4; ++df) {
          bf16x8 bV = *(const bf16x8*)(&Vtl[buf][0] +
                                       swz((uint32_t)((df * 16 + l15) * 128 + kf * 64 + g * 16)));
          acc[df] = __builtin_amdgcn_mfma_f32_16x16x32_bf16(aP, bV, acc[df], 0, 0, 0);
        }
      }
    }
    __syncthreads();
  }

  // epilogue: out[b, 2*(s*512+m), d] = acc (even rows; odd rows zeroed by zrec)
  const int b = bs >> 4, s = bs & 15;
  float* ob = out + (size_t)b * 1048576;
#pragma unroll
  for (int df = 0; df < 4; ++df)
#pragma unroll
    for (int r = 0; r < 4; ++r) {
      int m_ = m0w + g * 4 + r;
      ob[(size_t)(2 * (s * 512 + m_)) * 64 + df * 16 + l15] = acc[df][r];
    }
}

extern "C" void kernel_launch(void* const* d_in, const int* in_sizes, int n_in,
                              void* d_out, int out_size, void* d_ws, size_t ws_size,
                              hipStream_t stream) {
  const float* x  = (const float*)d_in[0];
  const float* Wk = (const float*)d_in[1];
  const float* Wq = (const float*)d_in[2];
  const float* Wv = (const float*)d_in[3];
  const float* PE = (const float*)d_in[4];
  float* out = (float*)d_out;
  char* ws = (char*)d_ws;

  ushort* Qw   = (ushort*)(ws);              // 8 MB
  ushort* Kw   = (ushort*)(ws + 8388608);    // 8 MB
  ushort* Vw   = (ushort*)(ws + 16777216);   // 8 MB
  ushort* Wp   = (ushort*)(ws + 25165824);   // 192 KB
  float*  PEdT = (float*)(ws + 25362432);    // 1 MB
  float*  rZ   = (float*)(ws + 26411008);    // 256 KB

  pack_kernel<<<dim3(1408), dim3(256), 0, stream>>>(Wk, Wq, Wv, PE, Wp, PEdT);
  proj_kernel<<<dim3(512), dim3(512), 0, stream>>>(x, Wp, Qw, Kw, Vw);
  zrec_kernel<<<dim3(512), dim3(512), 0, stream>>>(Qw, Kw, PEdT, rZ, out);
  attn_kernel<<<dim3(512), dim3(512), 0, stream>>>(Qw, Kw, Vw, PEdT, rZ, out);
}